// Round 7
// baseline (51593.958 us; speedup 1.0000x reference)
//
#include <hip/hip_runtime.h>

// 2-layer LSTM (B=256,S=100,F=256,H=1024) encode + 199 AR decode steps.
// Round 13 = FUSED CELL restructure: kill the P round-trip.
//   R10-R12 invariant: dur ~= hbm_bytes / 570 GB/s -> traffic-rate-bound.
//   P partials (K-split) were 67 of 74 MB/step. New partition: 256 WGs x
//   FULL-K x N-tile 16 gate-rows (4 gates x 4 hcols, wg owns hcols wg*4..+3).
//   MFMA acc holds complete gate pre-activations -> 3x shfl_xor(4/8/12)
//   gathers i,f,g,o to the g==0 lanes -> gate math in registers -> h written
//   directly. P buffer GONE, gate phases GONE, barriers 1396 -> ~800.
//   Per-WG fragment counts/LDS/MFMA identical to R12 (SLOTS_WG=13312,
//   W1 128KB LDS-resident, 240/384 MFMA per wave); only the pre-swizzle
//   row map changes: frag-row r -> weight row (r>>2)*1024 + wg*4 + (r&3).
//   h-state double-buffered (in-place update would race); ws SHRINKS to
//   62.4 MB (P region freed). c0/c1 single (owner-lane RMW only).
// Keep: 512 thr (2 waves/SIMD, R10-proven), tree barrier (R12-proven),
// fp16 hi/lo split precision (lo pre-scaled 2^11), cached reads + release
// fetch_add / acquire-fence coherence protocol (R8-proven).

#define S_   100
#define OUTC 300
#define NTHR 512

typedef __attribute__((ext_vector_type(8))) _Float16 half8;
typedef __attribute__((ext_vector_type(4))) float    floatx4;

// ---- workspace layout (bytes); total 62,398,720 (~59.5 MB) ----
#define OFF_C0     0u           // 256*1024*4 = 1,048,576
#define OFF_C1     1048576u
#define OFF_H      2097152u     // 8 x 524,288: [buf0|buf1] x {h0hi,h0lo,h1hi,h1lo}
#define OFF_BAR2   6291456u     // tree barrier: 33 slots x 256 B = 8448
#define OFF_LASTF  6299904u     // 256*256*4
#define OFF_LASTHI 6562048u     // 256*256*2
#define OFF_LASTLO 6693120u
#define OFF_OWHI   6824192u     // 256*1024*2
#define OFF_OWLO   7348480u
#define OFF_WFRAG  7872768u     // 256 WGs * 13312 slots * 16 B = 54,525,952
#define NEED_WS    62398720ull

#define NZ_WORDS   1574976      // zero [0, OFF_LASTF): c0,c1,h bufs,bar2
#define N_OW       262144
#define N_OUT0     65536
#define SLOTS_WG   13312        // per-WG: L0hi 2560 | L0lo 2560 | L1hi 4096 | L1lo 4096
#define N_FRAG     3407872      // 256*13312

#define BAR_STRIDE 64           // 64 u32 = 256 B per tree-barrier slot
#define LDS_BYTES  131072       // 8192 half8: W1hi [0,4096) | W1lo [4096,8192)

struct KParams {
  const float* x;
  const float* b0; const float* b1;
  const float* out_b; const float* dy_mu; const float* dy_std;
  const _Float16* OWhi; const _Float16* OWlo;
  const half8* wfrag;
  float* c0; float* c1; float* lastf;
  _Float16* hs;                 // 8-array h-state block (double-buffered)
  _Float16 *lasthi, *lastlo;
  unsigned* bar2;
  float* out;
};

__device__ __forceinline__ float fsig(float x)  { return 1.f / (1.f + __expf(-x)); }
__device__ __forceinline__ float ftanh_(float x){ float e = __expf(2.f*x); return 1.f - 2.f/(e + 1.f); }

__device__ __forceinline__ floatx4 mfma16h(half8 a, half8 b, floatx4 c){
  return __builtin_amdgcn_mfma_f32_16x16x32_f16(a, b, c, 0, 0, 0);
}

// Two-level tree barrier, 256 WGs, monotone counters (R12-proven).
// Release fetch_add on leaf (wbl2 flush of this WG's h/c stores) ->
// root RMW by leaf closer -> epoch broadcast to 16 flag lines ->
// relaxed poll on own leaf's flag -> ONE acquire fence (inv).
__device__ __forceinline__ void treebar(unsigned* b2, unsigned& ep, int wg){
  __syncthreads();
  if (threadIdx.x == 0) {
    ep += 1u;
    const int leaf = wg >> 4;
    unsigned a = __hip_atomic_fetch_add(&b2[leaf*BAR_STRIDE], 1u,
                                        __ATOMIC_RELEASE, __HIP_MEMORY_SCOPE_AGENT);
    if ((a & 15u) == 15u) {
      unsigned r = __hip_atomic_fetch_add(&b2[16*BAR_STRIDE], 1u,
                                          __ATOMIC_RELAXED, __HIP_MEMORY_SCOPE_AGENT);
      if ((r & 15u) == 15u) {
        unsigned newep = (r >> 4) + 1u;
        #pragma unroll
        for (int i = 0; i < 16; ++i)
          __hip_atomic_store(&b2[(17 + i)*BAR_STRIDE], newep,
                             __ATOMIC_RELEASE, __HIP_MEMORY_SCOPE_AGENT);
      }
    }
    while (__hip_atomic_load(&b2[(17 + leaf)*BAR_STRIDE],
                             __ATOMIC_RELAXED, __HIP_MEMORY_SCOPE_AGENT) < ep) {
      __builtin_amdgcn_s_sleep(4);
    }
    __builtin_amdgcn_fence(__ATOMIC_ACQUIRE, "agent");
  }
  __syncthreads();
}

// Split fp32 -> fp16 hi + scaled lo (lo = (v-hi)*2^11).
__device__ __forceinline__ void split2(float v, _Float16& hi, _Float16& lo){
  _Float16 h = (_Float16)v;
  hi = h;
  lo = (_Float16)((v - (float)h) * 2048.0f);
}

// FUSED LSTM cell phase: full-K GEMM (3-term split precision) + in-register
// gate math + direct h/c write. WG owns N-tile = 16 gate-rows (4 gates x
// 4 hcols at hcol base nt*4). 8 waves x 32 M-rows each (acc[2]).
// A cols [0,kb): xf fp32 (X32) or xhi/xlo fp16 pair (stride strX);
// [kb,..): hhi/hlo (stride 1024). B frags: BLDS ? LDS (W1) : global (W0).
// C/D frag col l15 = gate*4+hc -> gates of one hcol live in lanes l^4/8/12;
// three shfl_xor gather i,f,g,o to the g==0 lanes which write.
template<int NKT, bool X32, bool BLDS>
__device__ __forceinline__ void cell_phase(
    const float* __restrict__ xf, int strXf,
    const _Float16* __restrict__ xhi, const _Float16* __restrict__ xlo, int strX,
    int kb,
    const _Float16* __restrict__ hhi, const _Float16* __restrict__ hlo,
    const half8* __restrict__ bhiP, const half8* __restrict__ bloP,
    float* __restrict__ cbuf,
    _Float16* __restrict__ hhiW, _Float16* __restrict__ hloW,
    const float* __restrict__ bias, int nt)
{
  const int wv  = threadIdx.x >> 6;   // 0..7
  const int l   = threadIdx.x & 63;
  const int l15 = l & 15;
  const int lk  = (l >> 4) << 3;

  int mrow[2];
  #pragma unroll
  for (int mt = 0; mt < 2; ++mt) mrow[mt] = wv*32 + mt*16 + l15;

  floatx4 acc[2]  = {};
  floatx4 accl[2] = {};

  #pragma unroll 2
  for (int kt = 0; kt < NKT; ++kt) {
    const int k0 = kt*32;
    half8 ahi[2], alo[2];
    if (k0 < kb) {
      if (X32) {
        #pragma unroll
        for (int mt = 0; mt < 2; ++mt) {
          const float* p = xf + (size_t)mrow[mt]*strXf + k0 + lk;
          #pragma unroll
          for (int j = 0; j < 8; ++j) {
            float w = p[j];
            _Float16 h = (_Float16)w;
            ahi[mt][j] = h;
            alo[mt][j] = (_Float16)((w - (float)h) * 2048.0f);
          }
        }
      } else {
        #pragma unroll
        for (int mt = 0; mt < 2; ++mt) {
          size_t off = (size_t)mrow[mt]*strX + k0 + lk;
          ahi[mt] = *(const half8*)(xhi + off);
          alo[mt] = *(const half8*)(xlo + off);
        }
      }
    } else {
      #pragma unroll
      for (int mt = 0; mt < 2; ++mt) {
        size_t off = (size_t)mrow[mt]*1024 + (k0 - kb) + lk;
        ahi[mt] = *(const half8*)(hhi + off);
        alo[mt] = *(const half8*)(hlo + off);
      }
    }
    half8 bhi, blo;
    if constexpr (BLDS) {
      extern __shared__ half8 smem[];
      bhi = smem[kt*64 + l];
      blo = smem[4096 + kt*64 + l];
    } else {
      bhi = bhiP[kt*64 + l];
      blo = bloP[kt*64 + l];
    }
    #pragma unroll
    for (int mt = 0; mt < 2; ++mt) {
      acc[mt]  = mfma16h(ahi[mt], bhi, acc[mt]);
      accl[mt] = mfma16h(alo[mt], bhi, accl[mt]);
      accl[mt] = mfma16h(ahi[mt], blo, accl[mt]);
    }
  }

  // ---- fused gate epilogue ----
  const int g    = l15 >> 2;          // this lane's gate index (C col = g*4+hc)
  const int hc   = l15 & 3;
  const int hcol = nt*4 + hc;
  const float bI = bias[hcol], bF = bias[1024+hcol],
              bG = bias[2048+hcol], bO = bias[3072+hcol];
  #pragma unroll
  for (int mt = 0; mt < 2; ++mt)
    #pragma unroll
    for (int p = 0; p < 4; ++p) {
      float v  = acc[mt][p] + accl[mt][p] * (1.0f/2048.0f);
      float s4  = __shfl_xor(v, 4);    // same row/hc, gate^1
      float s8  = __shfl_xor(v, 8);    // gate^2
      float s12 = __shfl_xor(v, 12);   // gate^3
      if (g == 0) {                    // i-lane gathers f,g,o
        float gi = v + bI, gf = s4 + bF, gG = s8 + bG, go = s12 + bO;
        int m   = wv*32 + mt*16 + (l >> 4)*4 + p;  // C/D row=(lane>>4)*4+reg
        int idx = m*1024 + hcol;
        float c = fsig(gf) * cbuf[idx] + fsig(gi) * ftanh_(gG);
        cbuf[idx] = c;
        float h = fsig(go) * ftanh_(c);
        split2(h, hhiW[idx], hloW[idx]);
      }
    }
}

// OUT: wave 0 only. WG b owns the (mo=b&15, no=b>>4) 16x16 tile of
// dx = h1 @ outW^T over full K=1024.  mode 0: encode; 1: seed last; 2: decode.
__device__ __forceinline__ void out_phase_w0(
    const _Float16* __restrict__ h1hi, const _Float16* __restrict__ h1lo,
    const _Float16* __restrict__ OWhi, const _Float16* __restrict__ OWlo,
    const float* __restrict__ out_b, const float* __restrict__ dy_mu,
    const float* __restrict__ dy_std,
    const float* __restrict__ xcol, float* __restrict__ outcol,
    float* __restrict__ lastf, _Float16* __restrict__ lasthi, _Float16* __restrict__ lastlo,
    int mode)
{
  const int l   = threadIdx.x;     // 0..63 (wave 0)
  const int l15 = l & 15;
  const int lk  = (l >> 4) << 3;
  const int mo = blockIdx.x & 15, no = blockIdx.x >> 4;

  floatx4 acc = {}, accl = {};
  #pragma unroll 4
  for (int kt = 0; kt < 32; ++kt) {
    int k = kt*32 + lk;
    half8 a  = *(const half8*)(h1hi + (mo*16 + l15)*1024 + k);
    half8 al = *(const half8*)(h1lo + (mo*16 + l15)*1024 + k);
    half8 b  = *(const half8*)(OWhi + (no*16 + l15)*1024 + k);
    half8 bl = *(const half8*)(OWlo + (no*16 + l15)*1024 + k);
    acc  = mfma16h(a,  b,  acc);
    accl = mfma16h(al, b,  accl);
    accl = mfma16h(a,  bl, accl);
  }
  #pragma unroll
  for (int p = 0; p < 4; ++p) {
    float s = acc[p] + accl[p] * (1.0f/2048.0f);
    int m = mo*16 + (l >> 4)*4 + p;   // C/D: row=(lane>>4)*4+reg
    int f = no*16 + l15;              //      col=lane&15
    s += out_b[f];
    if (mode == 2) {
      float dxt = dy_std[f]*s + dy_mu[f];
      float nl = lastf[m*256+f] + dxt;
      lastf[m*256+f] = nl;
      outcol[(size_t)m*(OUTC*256) + f] = nl;
      split2(nl, lasthi[m*256+f], lastlo[m*256+f]);
    } else {
      float o = xcol[m*25600 + f] + s;
      outcol[(size_t)m*(OUTC*256) + f] = o;
      if (mode == 1) { lastf[m*256+f] = o; split2(o, lasthi[m*256+f], lastlo[m*256+f]); }
    }
  }
}

__global__ void __launch_bounds__(NTHR, 2) lstm_persist(KParams kp)
{
  const int wg = blockIdx.x;          // = nt (hcol base wg*4)
  unsigned ep = 0;

  const half8* W0hi = kp.wfrag + (size_t)wg * SLOTS_WG;
  const half8* W0lo = W0hi + 2560;

  // ---- one-time: copy this WG's W1 slice (hi|lo, 8192 half8) into LDS ----
  {
    extern __shared__ half8 smem[];
    const half8* src = kp.wfrag + (size_t)wg * SLOTS_WG + 5120;
    for (int i = threadIdx.x; i < 8192; i += NTHR) smem[i] = src[i];
    __syncthreads();
  }

  // double-buffered h state: R = previous step's h, W = this step's h
  _Float16 *h0hR = kp.hs + 1048576,          *h0lR = kp.hs + 1048576 + 262144,
           *h1hR = kp.hs + 1048576 + 524288, *h1lR = kp.hs + 1048576 + 786432;
  _Float16 *h0hW = kp.hs,                    *h0lW = kp.hs + 262144,
           *h1hW = kp.hs + 524288,           *h1lW = kp.hs + 786432;
  #define SWP(a,b) { _Float16* _t = a; a = b; b = _t; }
  #define SWAPALL() { SWP(h0hR,h0hW) SWP(h0lR,h0lW) SWP(h1hR,h1hW) SWP(h1lR,h1lW) }

  // ---------------- encode ----------------
  for (int t = 0; t < S_; ++t) {
    cell_phase<40, true, false>(kp.x + t*256, 25600, nullptr, nullptr, 0, 256,
                                h0hR, h0lR, W0hi, W0lo,
                                kp.c0, h0hW, h0lW, kp.b0, wg);
    if (t > 0 && threadIdx.x < 64)
      out_phase_w0(h1hR, h1lR, kp.OWhi, kp.OWlo,
                   kp.out_b, kp.dy_mu, kp.dy_std,
                   kp.x + (t-1)*256, kp.out + (size_t)t*256,
                   kp.lastf, kp.lasthi, kp.lastlo, 0);
    treebar(kp.bar2, ep, wg);
    cell_phase<64, false, true>(nullptr, 0, h0hW, h0lW, 1024, 1024,
                                h1hR, h1lR, nullptr, nullptr,
                                kp.c1, h1hW, h1lW, kp.b1, wg);
    treebar(kp.bar2, ep, wg);
    SWAPALL();
  }
  if (threadIdx.x < 64)
    out_phase_w0(h1hR, h1lR, kp.OWhi, kp.OWlo,     // h1_99 (post-swap R)
                 kp.out_b, kp.dy_mu, kp.dy_std,
                 kp.x + 99*256, kp.out + (size_t)100*256,
                 kp.lastf, kp.lasthi, kp.lastlo, 1);
  treebar(kp.bar2, ep, wg);

  // ---------------- decode ----------------
  for (int u = 0; u < 199; ++u) {
    cell_phase<40, false, false>(nullptr, 0, kp.lasthi, kp.lastlo, 256, 256,
                                 h0hR, h0lR, W0hi, W0lo,
                                 kp.c0, h0hW, h0lW, kp.b0, wg);
    treebar(kp.bar2, ep, wg);
    cell_phase<64, false, true>(nullptr, 0, h0hW, h0lW, 1024, 1024,
                                h1hR, h1lR, nullptr, nullptr,
                                kp.c1, h1hW, h1lW, kp.b1, wg);
    treebar(kp.bar2, ep, wg);
    if (threadIdx.x < 64)
      out_phase_w0(h1hW, h1lW, kp.OWhi, kp.OWlo,   // h1 of this step
                   kp.out_b, kp.dy_mu, kp.dy_std,
                   nullptr, kp.out + (size_t)(101+u)*256,
                   kp.lastf, kp.lasthi, kp.lastlo, 2);
    treebar(kp.bar2, ep, wg);
    SWAPALL();
  }
  #undef SWAPALL
  #undef SWP
}

// Init: zero [c0,c1,h-bufs,bar2], outW -> fp16 hi/lo, out[:,0,:] = x[:,0,:],
// split+swizzle weight fragments into per-WG slices.
// New frag map: frag-row r -> weight row (r>>2)*1024 + wg*4 + (r&3), full K.
__global__ void pre_kernel(const float* __restrict__ x, const float* __restrict__ outW,
                           const float* __restrict__ Wih0, const float* __restrict__ Whh0,
                           const float* __restrict__ Wih1, const float* __restrict__ Whh1,
                           _Float16* __restrict__ OWhi, _Float16* __restrict__ OWlo,
                           unsigned* __restrict__ zeroReg, float* __restrict__ out,
                           half8* __restrict__ wfrag)
{
  const int total = NZ_WORDS + N_OW + N_OUT0 + N_FRAG;
  for (int i = blockIdx.x*256 + threadIdx.x; i < total; i += gridDim.x*256) {
    if (i < NZ_WORDS) {
      zeroReg[i] = 0u;
    } else if (i < NZ_WORDS + N_OW) {
      int j = i - NZ_WORDS;
      split2(outW[j], OWhi[j], OWlo[j]);
    } else if (i < NZ_WORDS + N_OW + N_OUT0) {
      int j = i - (NZ_WORDS + N_OW);
      int m = j >> 8, f = j & 255;
      out[(size_t)m*(OUTC*256) + f] = x[m*25600 + f];
    } else {
      int fidx = i - (NZ_WORDS + N_OW + N_OUT0);
      int wg = fidx / SLOTS_WG;
      int r  = fidx - wg*SLOTS_WG;
      const float* src;
      bool lo;
      int kt, l;
      if (r < 5120) {          // layer 0: [0,2560) hi | [2560,5120) lo; K=1280
        lo = (r >= 2560);
        int rr = lo ? r - 2560 : r;
        kt = rr >> 6; l = rr & 63;
        int row = ((l & 15) >> 2)*1024 + wg*4 + (l & 3);
        int k = kt*32 + ((l >> 4) << 3);
        src = (k < 256) ? (Wih0 + (size_t)row*256 + k)
                        : (Whh0 + (size_t)row*1024 + (k - 256));
      } else {                 // layer 1: [5120,9216) hi | [9216,13312) lo; K=2048
        int r2 = r - 5120;
        lo = (r2 >= 4096);
        int rr = lo ? r2 - 4096 : r2;
        kt = rr >> 6; l = rr & 63;
        int row = ((l & 15) >> 2)*1024 + wg*4 + (l & 3);
        int k = kt*32 + ((l >> 4) << 3);
        src = (k < 1024) ? (Wih1 + (size_t)row*1024 + k)
                         : (Whh1 + (size_t)row*1024 + (k - 1024));
      }
      half8 v;
      #pragma unroll
      for (int j = 0; j < 8; ++j) {
        float w = src[j];
        _Float16 h = (_Float16)w;
        v[j] = lo ? (_Float16)((w - (float)h) * 2048.0f) : h;
      }
      wfrag[(size_t)wg*SLOTS_WG + r] = v;
    }
  }
}

// Diagnostic sentinel: encodes an error class+code into out[0].
__global__ void sent_kernel(float* out, float v) { out[0] = v; }

extern "C" void kernel_launch(void* const* d_in, const int* in_sizes, int n_in,
                              void* d_out, int out_size, void* d_ws, size_t ws_size,
                              hipStream_t stream)
{
  (void)in_sizes; (void)n_in; (void)out_size;
  char* ws = (char*)d_ws;
  float* out = (float*)d_out;

  if (ws_size < (size_t)NEED_WS) {
    sent_kernel<<<1, 1, 0, stream>>>(out, 900000.0f + 10.0f * (float)(ws_size >> 20));
    return;
  }

  const float* x    = (const float*)d_in[0];
  const float* Wih0 = (const float*)d_in[1];
  const float* Whh0 = (const float*)d_in[2];
  const float* Wih1 = (const float*)d_in[4];
  const float* Whh1 = (const float*)d_in[5];
  const float* outW = (const float*)d_in[7];

  KParams kp;
  kp.x     = x;
  kp.b0    = (const float*)d_in[3];
  kp.b1    = (const float*)d_in[6];
  kp.out_b = (const float*)d_in[8];
  kp.dy_mu = (const float*)d_in[9];
  kp.dy_std= (const float*)d_in[10];

  kp.c0     = (float*)(ws + OFF_C0);
  kp.c1     = (float*)(ws + OFF_C1);
  kp.hs     = (_Float16*)(ws + OFF_H);
  kp.bar2   = (unsigned*)(ws + OFF_BAR2);
  kp.lastf  = (float*)(ws + OFF_LASTF);
  kp.lasthi = (_Float16*)(ws + OFF_LASTHI);
  kp.lastlo = (_Float16*)(ws + OFF_LASTLO);
  kp.OWhi   = (const _Float16*)(ws + OFF_OWHI);
  kp.OWlo   = (const _Float16*)(ws + OFF_OWLO);
  kp.wfrag  = (const half8*)(ws + OFF_WFRAG);
  kp.out    = out;

  (void)hipGetLastError();  // clear any stale error
  pre_kernel<<<4096, 256, 0, stream>>>(x, outW, Wih0, Whh0, Wih1, Whh1,
      (_Float16*)(ws + OFF_OWHI), (_Float16*)(ws + OFF_OWLO),
      (unsigned*)ws, out,
      (half8*)(ws + OFF_WFRAG));
  hipError_t e1 = hipGetLastError();
  if (e1 != hipSuccess) {
    sent_kernel<<<1, 1, 0, stream>>>(out, 300000.0f + 10.0f * (float)e1);
    return;
  }

  (void)hipFuncSetAttribute((const void*)lstm_persist,
                            hipFuncAttributeMaxDynamicSharedMemorySize, LDS_BYTES);

  void* args[] = { &kp };
  hipError_t e2 = hipLaunchCooperativeKernel((const void*)lstm_persist,
                                             dim3(256), dim3(NTHR), args, LDS_BYTES, stream);
  if (e2 != hipSuccess) {
    (void)hipGetLastError();  // clear
    lstm_persist<<<256, NTHR, LDS_BYTES, stream>>>(kp);
    hipError_t e3 = hipGetLastError();
    if (e3 != hipSuccess) {
      sent_kernel<<<1, 1, 0, stream>>>(out, 500000.0f + 10.0f * (float)e3);
      return;
    }
  }
}

// Round 8
// 38572.021 us; speedup vs baseline: 1.3376x; 1.3376x over previous
//
#include <hip/hip_runtime.h>

// 2-layer LSTM (B=256,S=100,F=256,H=1024) encode + 199 AR decode steps.
// Round 14 = R12 base (best verified 39.2ms: 512thr, K-split P-tile partition,
// tree barrier, cached reads + release/acquire protocol) with TWO mechanical
// changes (both "LDS beats post-inv cold refetch", the R8-proven mechanism):
//   R13 post-mortem: fused full-K cell REGRESSED 24% (traffic -34% but per-wave
//   load-instr count x2 -> stall-bound). dur=bytes/570GB/s model falsified.
//   Reverted to R12 partition. New facts: all 32 WGs of an XCD share ks (same
//   A-slice, L2-shared); the inv's real victim is WG-PRIVATE weight slices
//   (W0 80KB/WG = 2.56MB/XCD cold from MALL every step, latency-exposed at
//   gemm0 phase start).
//   1) LDS re-plan: W0 hi+lo (80KB) + W1hi (64KB) resident in LDS (144KB);
//      only W1lo (64KB/WG) streamed from global. wfrag layout prefix [0,9216)
//      is exactly {W0hi|W0lo|W1hi} -> pre_kernel UNCHANGED, copy the prefix.
//      gemm0 loses all 80 global-B instrs/wave.
//   2) Decode out-phase parallelized across all 8 waves (was 1 wave, 128
//      serial loads, 7/8 machine idle): K-split 8-way + 8KB LDS scratch
//      reduction (LDS total 152KB <= 160), wave 0 does the epilogue.
// Skeleton: persistent 256 WGs, 1396 grid barriers, P-tile partition, fp16
// hi/lo split precision (lo pre-scaled 2^11), per-WG pre-swizzled slices.

#define S_   100
#define OUTC 300
#define NTHR 512

typedef __attribute__((ext_vector_type(8))) _Float16 half8;
typedef __attribute__((ext_vector_type(4))) float    floatx4;

// ---- workspace layout (bytes); base total 77,070,592 (~73.5 MB) ----
#define OFF_P       0u           // 256 tiles * 256*64 fp32 = 16,777,216
#define OFF_C0      16777216u    // 256*1024*4
#define OFF_C1      17825792u
#define OFF_H0HI    18874368u    // 256*1024*2 fp16
#define OFF_H0LO    19398656u
#define OFF_H1HI    19922944u
#define OFF_H1LO    20447232u
#define OFF_BAR     20971520u    // 256 B (legacy single-counter barrier)
#define OFF_LASTF   20971776u    // 256*256*4
#define OFF_LASTHI  21233920u    // 256*256*2
#define OFF_LASTLO  21364992u
#define OFF_OWHI    21496064u    // 256*1024*2
#define OFF_OWLO    22020352u
#define OFF_WFRAG   22544640u    // 256 WGs * 13312 slots * 16 B = 54,525,952
#define NEED_WS     77070592ull

// tree barrier block: 33 slots x 256 B = 8448 B appended at the end.
#define OFF_BAR2    77070592u
#define BAR2_WORDS  2112
#define BAR_STRIDE  64           // 64 u32 = 256 B per slot
#define NEED_WS2    (NEED_WS + 8448ull)

#define NZ_WORDS   1048640       // zero c0,c1,h0*,h1*,bar (4,194,560 B)
#define N_OW       262144
#define N_OUT0     65536
#define SLOTS_WG   13312         // per-WG: L0hi 2560 | L0lo 2560 | L1hi 4096 | L1lo 4096
#define N_FRAG     3407872       // 256*13312

// dynamic LDS: 9216 half8 weights (W0hi 0..2559 | W0lo 2560..5119 |
// W1hi 5120..9215) = 147456 B, then 512 floatx4 out-scratch = 8192 B.
#define LDS_WSLOTS 9216
#define SCR_OFF    147456
#define LDS_BYTES  155648

struct KParams {
  const float* x;
  const float* b0; const float* b1;
  const float* out_b; const float* dy_mu; const float* dy_std;
  const _Float16* OWhi; const _Float16* OWlo;
  const half8* wfrag;
  float* P; float* c0; float* c1; float* lastf;
  _Float16 *h0hi, *h0lo, *h1hi, *h1lo;
  _Float16 *lasthi, *lastlo;
  unsigned* bar;
  unsigned* bar2;   // tree barrier block (nullptr -> fall back to bar)
  float* out;
};

__device__ __forceinline__ float fsig(float x)  { return 1.f / (1.f + __expf(-x)); }
__device__ __forceinline__ float ftanh_(float x){ float e = __expf(2.f*x); return 1.f - 2.f/(e + 1.f); }

__device__ __forceinline__ floatx4 mfma16h(half8 a, half8 b, floatx4 c){
  return __builtin_amdgcn_mfma_f32_16x16x32_f16(a, b, c, 0, 0, 0);
}

// Legacy device-scope grid barrier (R8-proven): single monotone counter.
__device__ __forceinline__ void gridbar(unsigned* cnt){
  __syncthreads();
  if (threadIdx.x == 0) {
    unsigned arr = __hip_atomic_fetch_add(cnt, 1u, __ATOMIC_RELEASE, __HIP_MEMORY_SCOPE_AGENT);
    unsigned target = (arr & ~255u) + 256u;
    while (__hip_atomic_load(cnt, __ATOMIC_RELAXED, __HIP_MEMORY_SCOPE_AGENT) < target) {
      __builtin_amdgcn_s_sleep(4);
    }
    __builtin_amdgcn_fence(__ATOMIC_ACQUIRE, "agent");
  }
  __syncthreads();
}

// Two-level tree barrier, 256 WGs, monotone counters (R12-proven).
__device__ __forceinline__ void treebar(unsigned* b2, unsigned& ep, int wg){
  __syncthreads();
  if (threadIdx.x == 0) {
    ep += 1u;
    const int leaf = wg >> 4;
    unsigned a = __hip_atomic_fetch_add(&b2[leaf*BAR_STRIDE], 1u,
                                        __ATOMIC_RELEASE, __HIP_MEMORY_SCOPE_AGENT);
    if ((a & 15u) == 15u) {
      unsigned r = __hip_atomic_fetch_add(&b2[16*BAR_STRIDE], 1u,
                                          __ATOMIC_RELAXED, __HIP_MEMORY_SCOPE_AGENT);
      if ((r & 15u) == 15u) {
        unsigned newep = (r >> 4) + 1u;
        #pragma unroll
        for (int i = 0; i < 16; ++i)
          __hip_atomic_store(&b2[(17 + i)*BAR_STRIDE], newep,
                             __ATOMIC_RELEASE, __HIP_MEMORY_SCOPE_AGENT);
      }
    }
    while (__hip_atomic_load(&b2[(17 + leaf)*BAR_STRIDE],
                             __ATOMIC_RELAXED, __HIP_MEMORY_SCOPE_AGENT) < ep) {
      __builtin_amdgcn_s_sleep(4);
    }
    __builtin_amdgcn_fence(__ATOMIC_ACQUIRE, "agent");
  }
  __syncthreads();
}

// Split fp32 -> fp16 hi + scaled lo (lo = (v-hi)*2^11).
__device__ __forceinline__ void split2(float v, _Float16& hi, _Float16& lo){
  _Float16 h = (_Float16)v;
  hi = h;
  lo = (_Float16)((v - (float)h) * 2048.0f);
}

// K-split GEMM phase, 3-term split precision. 8 waves x 32 rows (acc[2][4]).
// B-fragments: BHIB/BLOB >= 0 -> LDS slot base; -1 -> global (bhiP/bloP).
// A cols [0,kb): xf fp32 (X32) or xhi/xlo pair (stride strX); [kb,..): hhi/hlo.
template<int NKT, bool X32, int BHIB, int BLOB>
__device__ __forceinline__ void gemm_phase(
    const float* __restrict__ xf, int strXf,
    const _Float16* __restrict__ xhi, const _Float16* __restrict__ xlo, int strX,
    int kb,
    const _Float16* __restrict__ hhi, const _Float16* __restrict__ hlo,
    const half8* __restrict__ bhiP, const half8* __restrict__ bloP, int kbase,
    float* __restrict__ Ppart, int nt, int ks)
{
  const int wv  = threadIdx.x >> 6;   // 0..7
  const int l   = threadIdx.x & 63;
  const int l15 = l & 15;
  const int lk  = (l >> 4) << 3;

  int mrow[2];
  #pragma unroll
  for (int mt = 0; mt < 2; ++mt) mrow[mt] = wv*32 + mt*16 + l15;

  floatx4 acc[2][4]  = {};
  floatx4 accl[2][4] = {};

  #pragma unroll 2
  for (int kt = 0; kt < NKT; ++kt) {
    const int k0 = kbase + kt*32;
    half8 ahi[2], alo[2];
    if (k0 < kb) {
      if (X32) {
        #pragma unroll
        for (int mt = 0; mt < 2; ++mt) {
          const float* p = xf + (size_t)mrow[mt]*strXf + k0 + lk;
          #pragma unroll
          for (int j = 0; j < 8; ++j) {
            float w = p[j];
            _Float16 h = (_Float16)w;
            ahi[mt][j] = h;
            alo[mt][j] = (_Float16)((w - (float)h) * 2048.0f);
          }
        }
      } else {
        #pragma unroll
        for (int mt = 0; mt < 2; ++mt) {
          size_t off = (size_t)mrow[mt]*strX + k0 + lk;
          ahi[mt] = *(const half8*)(xhi + off);
          alo[mt] = *(const half8*)(xlo + off);
        }
      }
    } else {
      #pragma unroll
      for (int mt = 0; mt < 2; ++mt) {
        size_t off = (size_t)mrow[mt]*1024 + (k0 - kb) + lk;
        ahi[mt] = *(const half8*)(hhi + off);
        alo[mt] = *(const half8*)(hlo + off);
      }
    }
    #pragma unroll
    for (int n = 0; n < 4; ++n) {
      half8 bhi, blo;
      if constexpr (BHIB >= 0) {
        extern __shared__ half8 smem[];
        bhi = smem[BHIB + (kt*4 + n)*64 + l];
      } else {
        bhi = bhiP[(kt*4 + n)*64 + l];
      }
      if constexpr (BLOB >= 0) {
        extern __shared__ half8 smem[];
        blo = smem[BLOB + (kt*4 + n)*64 + l];
      } else {
        blo = bloP[(kt*4 + n)*64 + l];
      }
      #pragma unroll
      for (int mt = 0; mt < 2; ++mt) {
        acc[mt][n]  = mfma16h(ahi[mt], bhi, acc[mt][n]);
        accl[mt][n] = mfma16h(alo[mt], bhi, accl[mt][n]);
        accl[mt][n] = mfma16h(ahi[mt], blo, accl[mt][n]);
      }
    }
  }

  float* pb = Ppart + (size_t)(ks*64 + nt) * (256*64);
  const int rbase = (l >> 4) * 4;
  #pragma unroll
  for (int mt = 0; mt < 2; ++mt)
    #pragma unroll
    for (int p = 0; p < 4; ++p) {
      int m = wv*32 + mt*16 + rbase + p;   // C/D: row=(lane>>4)*4+reg, col=lane&15
      #pragma unroll
      for (int n = 0; n < 4; ++n)
        pb[(size_t)m*64 + n*16 + l15] = acc[mt][n][p] + accl[mt][n][p] * (1.0f/2048.0f);
    }
}

// Sum 4 K-partials + bias -> i,f,g,o -> update c slice, write h slice (hi/lo).
__device__ __forceinline__ void gate_phase(
    const float* __restrict__ P, float* __restrict__ cbuf,
    _Float16* __restrict__ hhi, _Float16* __restrict__ hlo,
    const float* __restrict__ bias, int nt, int ks)
{
  #pragma unroll
  for (int j = 0; j < 2; ++j) {
    int id = j*NTHR + threadIdx.x;
    int ml = id >> 4, hc = id & 15;
    int m = ks*64 + ml, hcol = nt*16 + hc;
    float g[4];
    #pragma unroll
    for (int gg = 0; gg < 4; ++gg) {
      float s = bias[gg*1024 + hcol];
      #pragma unroll
      for (int k = 0; k < 4; ++k)
        s += P[(size_t)(k*64 + nt)*(256*64) + (size_t)m*64 + gg*16 + hc];
      g[gg] = s;
    }
    int idx = m*1024 + hcol;
    float c = fsig(g[1]) * cbuf[idx] + fsig(g[0]) * ftanh_(g[2]);
    cbuf[idx] = c;
    float h = fsig(g[3]) * ftanh_(c);
    split2(h, hhi[idx], hlo[idx]);
  }
}

// OUT, wave-0 form (encode modes 0/1, overlapped with gemm0 or standalone).
__device__ __forceinline__ void out_phase_w0(
    const _Float16* __restrict__ h1hi, const _Float16* __restrict__ h1lo,
    const _Float16* __restrict__ OWhi, const _Float16* __restrict__ OWlo,
    const float* __restrict__ out_b, const float* __restrict__ dy_mu,
    const float* __restrict__ dy_std,
    const float* __restrict__ xcol, float* __restrict__ outcol,
    float* __restrict__ lastf, _Float16* __restrict__ lasthi, _Float16* __restrict__ lastlo,
    int mode)
{
  const int l   = threadIdx.x;     // 0..63 (wave 0)
  const int l15 = l & 15;
  const int lk  = (l >> 4) << 3;
  const int mo = blockIdx.x & 15, no = blockIdx.x >> 4;

  floatx4 acc = {}, accl = {};
  #pragma unroll 4
  for (int kt = 0; kt < 32; ++kt) {
    int k = kt*32 + lk;
    half8 a  = *(const half8*)(h1hi + (mo*16 + l15)*1024 + k);
    half8 al = *(const half8*)(h1lo + (mo*16 + l15)*1024 + k);
    half8 b  = *(const half8*)(OWhi + (no*16 + l15)*1024 + k);
    half8 bl = *(const half8*)(OWlo + (no*16 + l15)*1024 + k);
    acc  = mfma16h(a,  b,  acc);
    accl = mfma16h(al, b,  accl);
    accl = mfma16h(a,  bl, accl);
  }
  #pragma unroll
  for (int p = 0; p < 4; ++p) {
    float s = acc[p] + accl[p] * (1.0f/2048.0f);
    int m = mo*16 + (l >> 4)*4 + p;   // C/D: row=(lane>>4)*4+reg
    int f = no*16 + l15;              //      col=lane&15
    s += out_b[f];
    if (mode == 2) {
      float dxt = dy_std[f]*s + dy_mu[f];
      float nl = lastf[m*256+f] + dxt;
      lastf[m*256+f] = nl;
      outcol[(size_t)m*(OUTC*256) + f] = nl;
      split2(nl, lasthi[m*256+f], lastlo[m*256+f]);
    } else {
      float o = xcol[m*25600 + f] + s;
      outcol[(size_t)m*(OUTC*256) + f] = o;
      if (mode == 1) { lastf[m*256+f] = o; split2(o, lasthi[m*256+f], lastlo[m*256+f]); }
    }
  }
}

// OUT, 8-wave form for decode (mode 2): K-split across the 8 waves (4 kt
// each), partials reduced through 8KB LDS scratch; wave 0 does the epilogue.
// Must be called by ALL 512 threads (contains __syncthreads).
__device__ __forceinline__ void out_phase_w8(
    const _Float16* __restrict__ h1hi, const _Float16* __restrict__ h1lo,
    const _Float16* __restrict__ OWhi, const _Float16* __restrict__ OWlo,
    const float* __restrict__ out_b, const float* __restrict__ dy_mu,
    const float* __restrict__ dy_std,
    float* __restrict__ outcol,
    float* __restrict__ lastf, _Float16* __restrict__ lasthi, _Float16* __restrict__ lastlo)
{
  const int wv  = threadIdx.x >> 6;
  const int l   = threadIdx.x & 63;
  const int l15 = l & 15;
  const int lk  = (l >> 4) << 3;
  const int mo = blockIdx.x & 15, no = blockIdx.x >> 4;

  extern __shared__ char smraw[];
  floatx4* scr = (floatx4*)(smraw + SCR_OFF);

  floatx4 acc = {}, accl = {};
  #pragma unroll
  for (int kt = wv*4; kt < wv*4 + 4; ++kt) {
    int k = kt*32 + lk;
    half8 a  = *(const half8*)(h1hi + (mo*16 + l15)*1024 + k);
    half8 al = *(const half8*)(h1lo + (mo*16 + l15)*1024 + k);
    half8 b  = *(const half8*)(OWhi + (no*16 + l15)*1024 + k);
    half8 bl = *(const half8*)(OWlo + (no*16 + l15)*1024 + k);
    acc  = mfma16h(a,  b,  acc);
    accl = mfma16h(al, b,  accl);
    accl = mfma16h(a,  bl, accl);
  }
  floatx4 tot;
  #pragma unroll
  for (int p = 0; p < 4; ++p) tot[p] = acc[p] + accl[p] * (1.0f/2048.0f);
  scr[wv*64 + l] = tot;
  __syncthreads();
  if (wv == 0) {
    floatx4 s = scr[l];
    #pragma unroll
    for (int w = 1; w < 8; ++w) {
      floatx4 t = scr[w*64 + l];
      #pragma unroll
      for (int p = 0; p < 4; ++p) s[p] += t[p];
    }
    #pragma unroll
    for (int p = 0; p < 4; ++p) {
      int m = mo*16 + (l >> 4)*4 + p;
      int f = no*16 + l15;
      float v = s[p] + out_b[f];
      float dxt = dy_std[f]*v + dy_mu[f];
      float nl = lastf[m*256+f] + dxt;
      lastf[m*256+f] = nl;
      outcol[(size_t)m*(OUTC*256) + f] = nl;
      split2(nl, lasthi[m*256+f], lastlo[m*256+f]);
    }
  }
  __syncthreads();
}

__global__ void __launch_bounds__(NTHR, 2) lstm_persist(KParams kp)
{
  const int nt = blockIdx.x >> 2, ks = blockIdx.x & 3;
  unsigned ep = 0;

  // W1lo stays global (streamed); everything else weight-wise is in LDS.
  const half8* W1loG = kp.wfrag + (size_t)blockIdx.x * SLOTS_WG + 9216;

  #define GBAR() do { if (kp.bar2) treebar(kp.bar2, ep, blockIdx.x); \
                      else gridbar(kp.bar); } while (0)

  // ---- one-time: copy W0hi|W0lo|W1hi (9216 half8 = 144 KB) into LDS ----
  {
    extern __shared__ half8 smem[];
    const half8* src = kp.wfrag + (size_t)blockIdx.x * SLOTS_WG;
    for (int i = threadIdx.x; i < LDS_WSLOTS; i += NTHR) smem[i] = src[i];
    __syncthreads();
  }

  // ---------------- encode ----------------
  for (int t = 0; t < S_; ++t) {
    gemm_phase<10, true, 0, 2560>(kp.x + t*256, 25600, nullptr, nullptr, 0, 256,
                         kp.h0hi, kp.h0lo, nullptr, nullptr, ks*320, kp.P, nt, ks);
    if (t > 0 && threadIdx.x < 64)
      out_phase_w0(kp.h1hi, kp.h1lo, kp.OWhi, kp.OWlo,
                   kp.out_b, kp.dy_mu, kp.dy_std,
                   kp.x + (t-1)*256, kp.out + (size_t)t*256,
                   kp.lastf, kp.lasthi, kp.lastlo, 0);
    GBAR();
    gate_phase(kp.P, kp.c0, kp.h0hi, kp.h0lo, kp.b0, nt, ks);
    GBAR();
    gemm_phase<16, false, 5120, -1>(nullptr, 0, kp.h0hi, kp.h0lo, 1024, 1024,
                          kp.h1hi, kp.h1lo, nullptr, W1loG, ks*512, kp.P, nt, ks);
    GBAR();
    gate_phase(kp.P, kp.c1, kp.h1hi, kp.h1lo, kp.b1, nt, ks);
    GBAR();
  }
  if (threadIdx.x < 64)
    out_phase_w0(kp.h1hi, kp.h1lo, kp.OWhi, kp.OWlo,
                 kp.out_b, kp.dy_mu, kp.dy_std,
                 kp.x + 99*256, kp.out + (size_t)100*256,
                 kp.lastf, kp.lasthi, kp.lastlo, 1);
  GBAR();

  // ---------------- decode ----------------
  for (int u = 0; u < 199; ++u) {
    gemm_phase<10, false, 0, 2560>(nullptr, 0, kp.lasthi, kp.lastlo, 256, 256,
                          kp.h0hi, kp.h0lo, nullptr, nullptr, ks*320, kp.P, nt, ks);
    GBAR();
    gate_phase(kp.P, kp.c0, kp.h0hi, kp.h0lo, kp.b0, nt, ks);
    GBAR();
    gemm_phase<16, false, 5120, -1>(nullptr, 0, kp.h0hi, kp.h0lo, 1024, 1024,
                          kp.h1hi, kp.h1lo, nullptr, W1loG, ks*512, kp.P, nt, ks);
    GBAR();
    gate_phase(kp.P, kp.c1, kp.h1hi, kp.h1lo, kp.b1, nt, ks);
    GBAR();
    out_phase_w8(kp.h1hi, kp.h1lo, kp.OWhi, kp.OWlo,
                 kp.out_b, kp.dy_mu, kp.dy_std,
                 kp.out + (size_t)(101+u)*256,
                 kp.lastf, kp.lasthi, kp.lastlo);
    GBAR();
  }
  #undef GBAR
}

// Init: zero states+barriers, outW -> fp16 hi/lo, out[:,0,:] = x[:,0,:],
// and split+swizzle all weight fragments into per-WG global slices.
// (Identical to R12 — the K-split frag map.)
__global__ void pre_kernel(const float* __restrict__ x, const float* __restrict__ outW,
                           const float* __restrict__ Wih0, const float* __restrict__ Whh0,
                           const float* __restrict__ Wih1, const float* __restrict__ Whh1,
                           _Float16* __restrict__ OWhi, _Float16* __restrict__ OWlo,
                           unsigned* __restrict__ zeroReg, float* __restrict__ out,
                           half8* __restrict__ wfrag, unsigned* __restrict__ bar2)
{
  if (bar2) {
    for (int i = blockIdx.x*256 + threadIdx.x; i < BAR2_WORDS; i += gridDim.x*256)
      bar2[i] = 0u;
  }
  const int total = NZ_WORDS + N_OW + N_OUT0 + N_FRAG;
  for (int i = blockIdx.x*256 + threadIdx.x; i < total; i += gridDim.x*256) {
    if (i < NZ_WORDS) {
      zeroReg[i] = 0u;
    } else if (i < NZ_WORDS + N_OW) {
      int j = i - NZ_WORDS;
      split2(outW[j], OWhi[j], OWlo[j]);
    } else if (i < NZ_WORDS + N_OW + N_OUT0) {
      int j = i - (NZ_WORDS + N_OW);
      int m = j >> 8, f = j & 255;
      out[(size_t)m*(OUTC*256) + f] = x[m*25600 + f];
    } else {
      int fidx = i - (NZ_WORDS + N_OW + N_OUT0);
      int wg = fidx / SLOTS_WG;
      int r  = fidx - wg*SLOTS_WG;
      int nt = wg >> 2, ks = wg & 3;
      const float* src;
      bool lo;
      if (r < 5120) {          // layer 0: slots [0,2560) hi, [2560,5120) lo
        lo = (r >= 2560);
        int rr = lo ? r - 2560 : r;
        int kt = rr >> 8, q = rr & 255, g = q >> 6, l = q & 63;
        int row = g*1024 + nt*16 + (l & 15);
        int k = ks*320 + kt*32 + ((l >> 4) << 3);
        src = (k < 256) ? (Wih0 + (size_t)row*256 + k)
                        : (Whh0 + (size_t)row*1024 + (k - 256));
      } else {                 // layer 1: [5120,9216) hi, [9216,13312) lo
        int r2 = r - 5120;
        lo = (r2 >= 4096);
        int rr = lo ? r2 - 4096 : r2;
        int kt = rr >> 8, q = rr & 255, g = q >> 6, l = q & 63;
        int row = g*1024 + nt*16 + (l & 15);
        int k = ks*512 + kt*32 + ((l >> 4) << 3);
        src = (k < 1024) ? (Wih1 + (size_t)row*1024 + k)
                         : (Whh1 + (size_t)row*1024 + (k - 1024));
      }
      half8 v;
      #pragma unroll
      for (int j = 0; j < 8; ++j) {
        float w = src[j];
        _Float16 h = (_Float16)w;
        v[j] = lo ? (_Float16)((w - (float)h) * 2048.0f) : h;
      }
      wfrag[(size_t)wg*SLOTS_WG + r] = v;
    }
  }
}

// Diagnostic sentinel: encodes an error class+code into out[0].
__global__ void sent_kernel(float* out, float v) { out[0] = v; }

extern "C" void kernel_launch(void* const* d_in, const int* in_sizes, int n_in,
                              void* d_out, int out_size, void* d_ws, size_t ws_size,
                              hipStream_t stream)
{
  (void)in_sizes; (void)n_in; (void)out_size;
  char* ws = (char*)d_ws;
  float* out = (float*)d_out;

  if (ws_size < (size_t)NEED_WS) {
    sent_kernel<<<1, 1, 0, stream>>>(out, 900000.0f + 10.0f * (float)(ws_size >> 20));
    return;
  }

  const float* x    = (const float*)d_in[0];
  const float* Wih0 = (const float*)d_in[1];
  const float* Whh0 = (const float*)d_in[2];
  const float* Wih1 = (const float*)d_in[4];
  const float* Whh1 = (const float*)d_in[5];
  const float* outW = (const float*)d_in[7];

  KParams kp;
  kp.x     = x;
  kp.b0    = (const float*)d_in[3];
  kp.b1    = (const float*)d_in[6];
  kp.out_b = (const float*)d_in[8];
  kp.dy_mu = (const float*)d_in[9];
  kp.dy_std= (const float*)d_in[10];

  kp.P      = (float*)(ws + OFF_P);
  kp.c0     = (float*)(ws + OFF_C0);
  kp.c1     = (float*)(ws + OFF_C1);
  kp.h0hi   = (_Float16*)(ws + OFF_H0HI);
  kp.h0lo   = (_Float16*)(ws + OFF_H0LO);
  kp.h1hi   = (_Float16*)(ws + OFF_H1HI);
  kp.h1lo   = (_Float16*)(ws + OFF_H1LO);
  kp.bar    = (unsigned*)(ws + OFF_BAR);
  kp.bar2   = (ws_size >= (size_t)NEED_WS2) ? (unsigned*)(ws + OFF_BAR2) : nullptr;
  kp.lastf  = (float*)(ws + OFF_LASTF);
  kp.lasthi = (_Float16*)(ws + OFF_LASTHI);
  kp.lastlo = (_Float16*)(ws + OFF_LASTLO);
  kp.OWhi   = (const _Float16*)(ws + OFF_OWHI);
  kp.OWlo   = (const _Float16*)(ws + OFF_OWLO);
  kp.wfrag  = (const half8*)(ws + OFF_WFRAG);
  kp.out    = out;

  (void)hipGetLastError();  // clear any stale error
  pre_kernel<<<4096, 256, 0, stream>>>(x, outW, Wih0, Whh0, Wih1, Whh1,
      (_Float16*)(ws + OFF_OWHI), (_Float16*)(ws + OFF_OWLO),
      (unsigned*)(ws + OFF_C0), out,
      (half8*)(ws + OFF_WFRAG), kp.bar2);
  hipError_t e1 = hipGetLastError();
  if (e1 != hipSuccess) {
    sent_kernel<<<1, 1, 0, stream>>>(out, 300000.0f + 10.0f * (float)e1);
    return;
  }

  // 152 KB dynamic LDS (gfx950 allows up to 160 KB/WG).
  (void)hipFuncSetAttribute((const void*)lstm_persist,
                            hipFuncAttributeMaxDynamicSharedMemorySize, LDS_BYTES);

  void* args[] = { &kp };
  hipError_t e2 = hipLaunchCooperativeKernel((const void*)lstm_persist,
                                             dim3(256), dim3(NTHR), args, LDS_BYTES, stream);
  if (e2 != hipSuccess) {
    (void)hipGetLastError();  // clear
    lstm_persist<<<256, NTHR, LDS_BYTES, stream>>>(kp);
    hipError_t e3 = hipGetLastError();
    if (e3 != hipSuccess) {
      sent_kernel<<<1, 1, 0, stream>>>(out, 500000.0f + 10.0f * (float)e3);
      return;
    }
  }
}